// Round 14
// baseline (150.488 us; speedup 1.0000x reference)
//
#include <hip/hip_runtime.h>
#include <math.h>

#define C_IN 2048
#define N_EXP 64
#define DELTA  3e-4f      // risky-gap threshold (>=100x expected logit error)
#define DELTA2 1e-3f      // candidate window around v2

typedef __bf16 bf16x8 __attribute__((ext_vector_type(8)));
typedef float f32x4 __attribute__((ext_vector_type(4)));

__device__ __forceinline__ ushort bf16_rne(float f) {
    uint u = __float_as_uint(f);
    u += 0x7FFFu + ((u >> 16) & 1u);
    return (ushort)(u >> 16);
}

// W [64][2048] fp32 -> frag-major bf16 hi/lo (r6 layout, refcheck'd r6-r13):
// o = (eg*64 + ks)*512 + lane*8 + j <-> e = eg*16+(lane&15), k = ks*32+(lane>>4)*8+j
__global__ void conv_w_kernel(const float* __restrict__ W,
                              ushort* __restrict__ whf, ushort* __restrict__ wlf) {
    const int o = blockIdx.x * 256 + threadIdx.x;   // 0..131071
    const int egks = o >> 9;
    const int lane = (o >> 3) & 63;
    const int j = o & 7;
    const int e = (egks >> 6) * 16 + (lane & 15);
    const int k = (egks & 63) * 32 + (lane >> 4) * 8 + j;
    const float f = W[e * C_IN + k];
    const ushort h = bf16_rne(f);
    whf[o] = h;
    wlf[o] = bf16_rne(f - __uint_as_float((uint)h << 16));
}

__device__ __forceinline__ void glds16(const void* g, void* l) {
    __builtin_amdgcn_global_load_lds(
        (const __attribute__((address_space(1))) uint32_t*)g,
        (__attribute__((address_space(3))) uint32_t*)l, 16, 0, 0);
}

// truncation-split: f = hi + lo with |f-hi-lo| ~ 2^-17|f| (4 VALU ops/float).
// hi error is compensated exactly by lo (lo = trunc-bf16 of the residual).
__device__ __forceinline__ void cvt8t(const float4 a, const float4 b,
                                      uint4& hv, uint4& lv) {
    const float fx[8] = {a.x, a.y, a.z, a.w, b.x, b.y, b.z, b.w};
#pragma unroll
    for (int p = 0; p < 4; ++p) {
        const uint u0 = __float_as_uint(fx[2 * p]);
        const uint u1 = __float_as_uint(fx[2 * p + 1]);
        const float d0 = fx[2 * p] - __uint_as_float(u0 & 0xFFFF0000u);
        const float d1 = fx[2 * p + 1] - __uint_as_float(u1 & 0xFFFF0000u);
        hv[p] = (u0 >> 16) | (u1 & 0xFFFF0000u);
        lv[p] = (__float_as_uint(d0) >> 16) | (__float_as_uint(d1) & 0xFFFF0000u);
    }
}

#define WAIT4 do { asm volatile("s_waitcnt vmcnt(4)" ::: "memory");           \
                   __builtin_amdgcn_sched_barrier(0); } while (0)
#define WAIT0 do { asm volatile("s_waitcnt vmcnt(0)" ::: "memory");           \
                   __builtin_amdgcn_sched_barrier(0); } while (0)

// issue W(JV+2) into ring slot WSLOT (two 1-KB contiguous L2 loads)
#define WISS2(JV, WSLOT) do {                                                 \
    glds16(whp + (size_t)((JV) + 2) * 512, wring + (WSLOT) * 2048 + l * 16);  \
    glds16(wlp + (size_t)((JV) + 2) * 512, wring + (WSLOT) * 2048 + 1024 + l * 16); \
    __builtin_amdgcn_sched_barrier(0);                                        \
} while (0)

// kstep body: A from x-LDS (swizzled fp32), B from ring slot, cvt, 3 MFMA
#define KBODY(JV, SLOT) do {                                                  \
    const int u_ = (JV) * 8 + kq * 2;                                         \
    float4 a0 = *(const float4*)(smem + tr * 8192 + ((u_ ^ sw) * 16));        \
    float4 a1 = *(const float4*)(smem + tr * 8192 + (((u_ + 1) ^ sw) * 16));  \
    uint4 bhu = *(const uint4*)(wring + (SLOT) * 2048 + l * 16);              \
    uint4 blu = *(const uint4*)(wring + (SLOT) * 2048 + 1024 + l * 16);       \
    uint4 hv, lv;                                                             \
    cvt8t(a0, a1, hv, lv);                                                    \
    bf16x8 ah = __builtin_bit_cast(bf16x8, hv);                               \
    bf16x8 al = __builtin_bit_cast(bf16x8, lv);                               \
    bf16x8 bh = __builtin_bit_cast(bf16x8, bhu);                              \
    bf16x8 bl = __builtin_bit_cast(bf16x8, blu);                              \
    __builtin_amdgcn_s_setprio(1);                                            \
    acc = __builtin_amdgcn_mfma_f32_16x16x32_bf16(ah, bh, acc, 0, 0, 0);      \
    acc = __builtin_amdgcn_mfma_f32_16x16x32_bf16(al, bh, acc, 0, 0, 0);      \
    acc = __builtin_amdgcn_mfma_f32_16x16x32_bf16(ah, bl, acc, 0, 0, 0);      \
    __builtin_amdgcn_s_setprio(0);                                            \
} while (0)

#define KS(JV, SLOT, WSLOT) do { WISS2(JV, WSLOT); WAIT4; KBODY(JV, SLOT); } while (0)

// Main: 256 blocks x 256 thr (4 waves), 152 KB LDS, 1 block/CU.
// Block = 64 tokens = one contiguous 512-KB x panel, processed as 4
// sub-panels of 16 tokens x full K (128 KB contiguous). Per sub-panel:
//   stage: 32 gload_lds/thread in ASCENDING ADDRESS ORDER (one long
//     sequential sweep -> stream-prefetch-friendly; ~512 lines in flight),
//     16-B-unit source swizzle (u ^ (row&7)) <-> same XOR on A-reads.
//   compute: 64 ksteps, barrier-free; W bf16 hi/lo ring-3 from L2 (frag-major
//     1-KB contiguous), issue-2-ahead, counted vmcnt(4) (single-stream FIFO);
//     fp32 A-read -> truncation-split cvt -> 3 MFMA (xh*wh + xl*wh + xh*wl).
//   epilogue: full logits (no K-split) -> verified softmax/top-2/fp32-repair.
__global__ __launch_bounds__(256) void topk_gate_kernel(
    const float* __restrict__ x, const float* __restrict__ Wf,
    const float* __restrict__ b, const ushort* __restrict__ whf,
    const ushort* __restrict__ wlf, float* __restrict__ out)
{
    // [0,131072): x sub-panel fp32 [16 rows][8192 B], 16-B units swizzled
    // [131072,155648): W rings, wave w at +w*6144, 3 slots x 2 KB (hi|lo)
    __shared__ __align__(16) char smem[155648];

    const int tid = threadIdx.x;
    const int w = tid >> 6, l = tid & 63;
    const int tr = l & 15, kq = l >> 4;
    const int sw = tr & 7;

    const ushort* whp = whf + (size_t)(w * 64) * 512 + l * 8;
    const ushort* wlp = wlf + (size_t)(w * 64) * 512 + l * 8;
    char* wring = smem + 131072 + w * 6144;

    const float be = b[l];

#pragma unroll 1
    for (int p = 0; p < 4; ++p) {
        const int tokBaseP = blockIdx.x * 64 + p * 16;
        const float* xgp = x + (size_t)tokBaseP * C_IN;

        // ---- W prologue (W0,W1 into slots 0,1; oldest in FIFO) ----
        WISS2(-2, 0);
        WISS2(-1, 1);

        // ---- stage 128 KB sequentially (ascending addresses) ----
#pragma unroll
        for (int j2 = 0; j2 < 32; ++j2) {
            const int r = j2 >> 1;                       // compile-time
            const int us = tid + (j2 & 1) * 256;         // 16-B unit in row
            const size_t srcU = (size_t)r * 512 + (us ^ (r & 7));
            glds16((const char*)xgp + srcU * 16, smem + j2 * 4096 + tid * 16);
        }
        __builtin_amdgcn_sched_barrier(0);
        __syncthreads();   // drains vmcnt(0)+lgkmcnt(0): panel + W0,W1 landed

        // ---- 64 ksteps, barrier-free; ring slots j%3; issue W(j+2) ----
        f32x4 acc = {0.f, 0.f, 0.f, 0.f};
        {   // peeled j=0,1,2 (their B-slices landed pre-drain)
            WISS2(0, 2); KBODY(0, 0);
            WISS2(1, 0); WAIT4; KBODY(1, 1);
            WISS2(2, 1); WAIT4; KBODY(2, 2);
        }
#pragma unroll 1
        for (int m = 0; m < 5; ++m) {
            const int jb = 3 + 12 * m;
            KS(jb + 0, 0, 2); KS(jb + 1, 1, 0); KS(jb + 2, 2, 1);
            KS(jb + 3, 0, 2); KS(jb + 4, 1, 0); KS(jb + 5, 2, 1);
            KS(jb + 6, 0, 2); KS(jb + 7, 1, 0); KS(jb + 8, 2, 1);
            KS(jb + 9, 0, 2); KS(jb + 10, 1, 0); KS(jb + 11, 2, 1);
        }
        {   // j=63: no issue, full drain
            WAIT0; KBODY(63, 0);
        }
        __syncthreads();   // all A-reads done before part overlay

        // ---- partials [16][65] fp32 (overlay panel LDS) ----
        float* part = (float*)smem;
#pragma unroll
        for (int r = 0; r < 4; ++r)
            part[(kq * 4 + r) * 65 + w * 16 + tr] = acc[r];
        __syncthreads();

        // ---- softmax + top-2 + fp32 repair (wave w: tokens w*4..w*4+3) ----
        const int e = l;
        for (int ti = 0; ti < 4; ++ti) {
            const int t = w * 4 + ti;
            float logit = part[t * 65 + e] + be;

            float v1, v2, v3; int i1, i2;
            for (int pass = 0; pass < 2; ++pass) {
                v1 = logit; i1 = e;
#pragma unroll
                for (int off = 32; off >= 1; off >>= 1) {
                    float ov = __shfl_xor(v1, off, 64);
                    int   oi = __shfl_xor(i1, off, 64);
                    if (ov > v1 || (ov == v1 && oi < i1)) { v1 = ov; i1 = oi; }
                }
                v2 = (e == i1) ? -3.4e38f : logit;
                i2 = (e == i1) ? N_EXP : e;
#pragma unroll
                for (int off = 32; off >= 1; off >>= 1) {
                    float ov = __shfl_xor(v2, off, 64);
                    int   oi = __shfl_xor(i2, off, 64);
                    if (ov > v2 || (ov == v2 && oi < i2)) { v2 = ov; i2 = oi; }
                }
                v3 = (e == i1 || e == i2) ? -3.4e38f : logit;
#pragma unroll
                for (int off = 32; off >= 1; off >>= 1) {
                    float ov = __shfl_xor(v3, off, 64);
                    v3 = (ov > v3) ? ov : v3;
                }
                if (pass == 1) break;
                const bool risky = (v1 - v2 < DELTA) || (v2 - v3 < DELTA);
                if (!risky) break;
                // exact fp32 recompute of candidate experts (wave-uniform)
                unsigned long long cm = __ballot(logit >= v2 - DELTA2);
                const float* xr = x + (size_t)(tokBaseP + t) * C_IN;
                while (cm) {
                    const int ce = __ffsll((unsigned long long)cm) - 1;
                    cm &= cm - 1;
                    const float* wr = Wf + (size_t)ce * C_IN;
                    float pr = 0.f;
#pragma unroll 8
                    for (int i = 0; i < 32; ++i)
                        pr = fmaf(xr[l + 64 * i], wr[l + 64 * i], pr);
#pragma unroll
                    for (int off = 32; off >= 1; off >>= 1)
                        pr += __shfl_xor(pr, off, 64);
                    if (e == ce) logit = pr + be;
                }
            }

            float ex = expf(logit - v1);
            float ssum = ex;
#pragma unroll
            for (int off = 32; off >= 1; off >>= 1)
                ssum += __shfl_xor(ssum, off, 64);
            const float inv = 1.0f / ssum;
            const float p1 = inv;
            const float p2 = expf(v2 - v1) * inv;
            const float o = (e == i1) ? p1 : ((e == i2) ? p2 : 0.0f);
            out[(size_t)(tokBaseP + t) * N_EXP + e] = o;
        }
        __syncthreads();   // epilogue done before next panel's stage
    }
}

extern "C" void kernel_launch(void* const* d_in, const int* in_sizes, int n_in,
                              void* d_out, int out_size, void* d_ws, size_t ws_size,
                              hipStream_t stream) {
    const float* x = (const float*)d_in[0];   // [4,4096,2048]
    const float* W = (const float*)d_in[1];   // [64,2048]
    const float* b = (const float*)d_in[2];   // [64]
    float* out = (float*)d_out;               // [4,4096,64]

    ushort* whf = (ushort*)d_ws;              // frag-major bf16 hi, 256 KB
    ushort* wlf = whf + N_EXP * C_IN;         // frag-major bf16 lo, 256 KB

    conv_w_kernel<<<512, 256, 0, stream>>>(W, whf, wlf);

    const int tokens = in_sizes[0] / C_IN;    // 16384
    const int grid = tokens / 64;             // 256
    topk_gate_kernel<<<grid, 256, 0, stream>>>(x, W, b, whf, wlf, out);
}

// Round 15
// 83.484 us; speedup vs baseline: 1.8026x; 1.8026x over previous
//
#include <hip/hip_runtime.h>
#include <math.h>

#define C_IN 2048
#define N_EXP 64
#define DELTA  3e-4f      // risky-gap threshold (>=100x expected logit error)
#define DELTA2 1e-3f      // candidate window around v2

typedef __bf16 bf16x8 __attribute__((ext_vector_type(8)));
typedef float f32x4 __attribute__((ext_vector_type(4)));

__device__ __forceinline__ ushort bf16_rne(float f) {
    uint u = __float_as_uint(f);
    u += 0x7FFFu + ((u >> 16) & 1u);
    return (ushort)(u >> 16);
}

// W [64][2048] fp32 -> frag-major bf16 hi/lo (r6 layout, refcheck'd r6-r14):
// o = (eg*64 + k)*512 + lane*8 + j <-> e = eg*16+(lane&15), kk = k*32+(lane>>4)*8+j
__global__ void conv_w_kernel(const float* __restrict__ W,
                              ushort* __restrict__ whf, ushort* __restrict__ wlf) {
    const int o = blockIdx.x * 256 + threadIdx.x;   // 0..131071
    const int egks = o >> 9;
    const int lane = (o >> 3) & 63;
    const int j = o & 7;
    const int e = (egks >> 6) * 16 + (lane & 15);
    const int k = (egks & 63) * 32 + (lane >> 4) * 8 + j;
    const float f = W[e * C_IN + k];
    const ushort h = bf16_rne(f);
    whf[o] = h;
    wlf[o] = bf16_rne(f - __uint_as_float((uint)h << 16));
}

__device__ __forceinline__ void glds16(const void* g, void* l) {
    __builtin_amdgcn_global_load_lds(
        (const __attribute__((address_space(1))) uint32_t*)g,
        (__attribute__((address_space(3))) uint32_t*)l, 16, 0, 0);
}

// truncation-split fp32 -> bf16 hi + bf16 lo (residual); verified r14
__device__ __forceinline__ void cvt8t(const float4 a, const float4 b,
                                      uint4& hv, uint4& lv) {
    const float fx[8] = {a.x, a.y, a.z, a.w, b.x, b.y, b.z, b.w};
#pragma unroll
    for (int p = 0; p < 4; ++p) {
        const uint x0 = __float_as_uint(fx[2 * p]);
        const uint x1 = __float_as_uint(fx[2 * p + 1]);
        const float d0 = fx[2 * p] - __uint_as_float(x0 & 0xFFFF0000u);
        const float d1 = fx[2 * p + 1] - __uint_as_float(x1 & 0xFFFF0000u);
        hv[p] = (x0 >> 16) | (x1 & 0xFFFF0000u);
        lv[p] = (__float_as_uint(d0) >> 16) | (__float_as_uint(d1) & 0xFFFF0000u);
    }
}

#define WLOAD(D, P) asm volatile("global_load_dwordx4 %0, %1, off"            \
                                 : "=&v"(D) : "v"(P) : "memory")

// issue W register-set for kstep K (8 x 16B, L2-resident, consumer-only FIFO)
#define WISSUE(SET, K) do {                                                   \
    _Pragma("unroll") for (int eg_ = 0; eg_ < 4; ++eg_) {                     \
        WLOAD(SET[eg_ * 2 + 0], whl + (size_t)(eg_ * 64 + (K)) * 512);        \
        WLOAD(SET[eg_ * 2 + 1], wll + (size_t)(eg_ * 64 + (K)) * 512);        \
    } } while (0)

// consumer kstep: A from panel LDS, counted wait (W-only FIFO), cvt, 12 MFMA,
// then re-issue this set for kstep KP2 (after consumption; in-order issue)
#define KSTEP(KS, SET, WN, DOISS, KP2) do {                                   \
    float4 a0 = *(const float4*)(sb + aoff[KS][0]);                           \
    float4 a1 = *(const float4*)(sb + aoff[KS][1]);                           \
    asm volatile("s_waitcnt vmcnt(" #WN ")" ::: "memory");                    \
    __builtin_amdgcn_sched_barrier(0);                                        \
    uint4 hv, lv;                                                             \
    cvt8t(a0, a1, hv, lv);                                                    \
    bf16x8 ah = __builtin_bit_cast(bf16x8, hv);                               \
    bf16x8 al = __builtin_bit_cast(bf16x8, lv);                               \
    __builtin_amdgcn_s_setprio(1);                                            \
    _Pragma("unroll") for (int eg_ = 0; eg_ < 4; ++eg_) {                     \
        bf16x8 bh = __builtin_bit_cast(bf16x8, SET[eg_ * 2 + 0]);             \
        bf16x8 bl = __builtin_bit_cast(bf16x8, SET[eg_ * 2 + 1]);             \
        acc[eg_] = __builtin_amdgcn_mfma_f32_16x16x32_bf16(ah, bh, acc[eg_], 0, 0, 0); \
        acc[eg_] = __builtin_amdgcn_mfma_f32_16x16x32_bf16(al, bh, acc[eg_], 0, 0, 0); \
        acc[eg_] = __builtin_amdgcn_mfma_f32_16x16x32_bf16(ah, bl, acc[eg_], 0, 0, 0); \
    }                                                                         \
    __builtin_amdgcn_s_setprio(0);                                            \
    if (DOISS) WISSUE(SET, KP2);                                              \
} while (0)

// Main: 512 blocks x 256 thr (4 waves) = 2 blocks/CU. Producer/consumer wave
// specialization: waves 0,1 = consumers (pair 0,1), waves 2,3 = producers.
// Pair p: tokens blockIdx*32 + p*16 .. +15.
// Producer: pure x streamer. 32 slices (64 cols = 256 B/row x 16 rows = 4 KB)
//   into a 4-slot LDS ring via 4 gload_lds each (16-B source swizzle
//   u^=(row&3)); keeps 3 slices (12 gloads, ~96 lines) in flight; publishes
//   via LDS flag after counted vmcnt(12); never computes, never drains.
// Consumer: spins on flag, A fp32 from ring (2 ds_read_b128, swizzle-matched),
//   truncation-split to bf16 hi/lo, W via inline-asm global_load_dwordx4 into
//   2 register sets (own pure-W vmcnt FIFO, ring-2, L2-resident), 12 MFMA per
//   kstep. Backpressure: cons_count flag. Epilogue wave-private (verified
//   softmax/top-2/fp32-repair). ONE __syncthreads (flag init) in the kernel.
__global__ __launch_bounds__(256, 2) void topk_gate_kernel(
    const float* __restrict__ x, const float* __restrict__ Wf,
    const float* __restrict__ b, const ushort* __restrict__ whf,
    const ushort* __restrict__ wlf, float* __restrict__ out)
{
    __shared__ __align__(16) char smem[32800];   // 2 x 16 KB panel rings + flags

    const int tid = threadIdx.x;
    const int w = tid >> 6, l = tid & 63;
    const int p = w & 1;
    const int t0p = blockIdx.x * 32 + p * 16;
    char* pbase = smem + p * 16384;
    volatile int* flags = (volatile int*)(smem + 32768);
    volatile int* prodc = flags + p;        // slices ready
    volatile int* consc = flags + 2 + p;    // slices consumed

    if (tid < 4) flags[tid] = 0;
    __syncthreads();   // the only barrier

    if (w >= 2) {
        // ---------------- producer: pure x stream ----------------
        const int r = l >> 2, u = l & 3;
        const char* src = (const char*)x + (size_t)(t0p + r) * 8192
                        + ((u ^ (r & 3)) * 16);
#pragma unroll 1
        for (int s = 0; s < 32; ++s) {
            if (s >= 4) { while (*consc < s - 3) __builtin_amdgcn_s_sleep(2); }
            char* dst = pbase + (s & 3) * 4096;
#pragma unroll
            for (int i = 0; i < 4; ++i)
                glds16(src + s * 256 + i * 64, dst + i * 1024);
            __builtin_amdgcn_sched_barrier(0);
            if (s >= 3) {
                asm volatile("s_waitcnt vmcnt(12)" ::: "memory");
                __builtin_amdgcn_sched_barrier(0);
                if (l == 0) *prodc = s - 2;   // slices 0..s-3 landed
            }
        }
        asm volatile("s_waitcnt vmcnt(0)" ::: "memory");
        __builtin_amdgcn_sched_barrier(0);
        if (l == 0) *prodc = 32;
        return;
    }

    // ---------------- consumer ----------------
    const int tr = l & 15, kg = l >> 4;
    const int u0 = ((kg * 2) & 3) ^ (tr & 3);
    const int u1 = ((kg * 2 + 1) & 3) ^ (tr & 3);
    int aoff[2][2];
#pragma unroll
    for (int ks = 0; ks < 2; ++ks) {
        const int ip = (ks * 2 + (kg >> 1)) * 1024 + tr * 64;
        aoff[ks][0] = ip + u0 * 16;
        aoff[ks][1] = ip + u1 * 16;
    }
    const ushort* whl = whf + l * 8;
    const ushort* wll = wlf + l * 8;

    uint4 wA[8], wB[8];
    f32x4 acc[4];
#pragma unroll
    for (int eg = 0; eg < 4; ++eg) acc[eg] = (f32x4){0.f, 0.f, 0.f, 0.f};

    WISSUE(wA, 0);
    WISSUE(wB, 1);

#pragma unroll 1
    for (int s = 0; s < 31; ++s) {
        while (*prodc < s + 1) __builtin_amdgcn_s_sleep(2);
        const char* sb = pbase + (s & 3) * 4096;
        KSTEP(0, wA, 8, 1, s * 2 + 2);
        KSTEP(1, wB, 8, 1, s * 2 + 3);
        if (l == 0) *consc = s + 1;
    }
    {   // s = 31: k=62 (no re-issue), k=63 (drain)
        while (*prodc < 32) __builtin_amdgcn_s_sleep(2);
        const char* sb = pbase + 3 * 4096;
        KSTEP(0, wA, 8, 0, 0);
        KSTEP(1, wB, 0, 0, 0);
        if (l == 0) *consc = 32;
    }

    // ---- epilogue (wave-private; ring region reused as part buffer) ----
    float* part = (float*)pbase;   // [16][65] fp32
#pragma unroll
    for (int eg = 0; eg < 4; ++eg)
#pragma unroll
    for (int r2 = 0; r2 < 4; ++r2)
        part[(kg * 4 + r2) * 65 + eg * 16 + tr] = acc[eg][r2];

    const int e = l;
    const float be = b[e];
    for (int ti = 0; ti < 16; ++ti) {
        float logit = part[ti * 65 + e] + be;

        float v1, v2, v3; int i1, i2;
        for (int pass = 0; pass < 2; ++pass) {
            v1 = logit; i1 = e;
#pragma unroll
            for (int off = 32; off >= 1; off >>= 1) {
                float ov = __shfl_xor(v1, off, 64);
                int   oi = __shfl_xor(i1, off, 64);
                if (ov > v1 || (ov == v1 && oi < i1)) { v1 = ov; i1 = oi; }
            }
            v2 = (e == i1) ? -3.4e38f : logit;
            i2 = (e == i1) ? N_EXP : e;
#pragma unroll
            for (int off = 32; off >= 1; off >>= 1) {
                float ov = __shfl_xor(v2, off, 64);
                int   oi = __shfl_xor(i2, off, 64);
                if (ov > v2 || (ov == v2 && oi < i2)) { v2 = ov; i2 = oi; }
            }
            v3 = (e == i1 || e == i2) ? -3.4e38f : logit;
#pragma unroll
            for (int off = 32; off >= 1; off >>= 1) {
                float ov = __shfl_xor(v3, off, 64);
                v3 = (ov > v3) ? ov : v3;
            }
            if (pass == 1) break;
            const bool risky = (v1 - v2 < DELTA) || (v2 - v3 < DELTA);
            if (!risky) break;
            // exact fp32 recompute of candidate experts (wave-uniform path)
            unsigned long long cm = __ballot(logit >= v2 - DELTA2);
            const float* xr = x + (size_t)(t0p + ti) * C_IN;
            while (cm) {
                const int ce = __ffsll((unsigned long long)cm) - 1;
                cm &= cm - 1;
                const float* wr = Wf + (size_t)ce * C_IN;
                float pr = 0.f;
#pragma unroll 8
                for (int i = 0; i < 32; ++i)
                    pr = fmaf(xr[l + 64 * i], wr[l + 64 * i], pr);
#pragma unroll
                for (int off = 32; off >= 1; off >>= 1)
                    pr += __shfl_xor(pr, off, 64);
                if (e == ce) logit = pr + be;
            }
        }

        float ex = expf(logit - v1);
        float ssum = ex;
#pragma unroll
        for (int off = 32; off >= 1; off >>= 1)
            ssum += __shfl_xor(ssum, off, 64);
        const float inv = 1.0f / ssum;
        const float p1 = inv;
        const float p2 = expf(v2 - v1) * inv;
        const float o = (e == i1) ? p1 : ((e == i2) ? p2 : 0.0f);
        out[(size_t)(t0p + ti) * N_EXP + e] = o;
    }
}

extern "C" void kernel_launch(void* const* d_in, const int* in_sizes, int n_in,
                              void* d_out, int out_size, void* d_ws, size_t ws_size,
                              hipStream_t stream) {
    const float* x = (const float*)d_in[0];   // [4,4096,2048]
    const float* W = (const float*)d_in[1];   // [64,2048]
    const float* b = (const float*)d_in[2];   // [64]
    float* out = (float*)d_out;               // [4,4096,64]

    ushort* whf = (ushort*)d_ws;              // frag-major bf16 hi, 256 KB
    ushort* wlf = whf + N_EXP * C_IN;         // frag-major bf16 lo, 256 KB

    conv_w_kernel<<<512, 256, 0, stream>>>(W, whf, wlf);

    const int tokens = in_sizes[0] / C_IN;    // 16384
    const int grid = tokens / 32;             // 512
    topk_gate_kernel<<<grid, 256, 0, stream>>>(x, W, b, whf, wlf, out);
}